// Round 16
// baseline (316.925 us; speedup 1.0000x reference)
//
#include <hip/hip_runtime.h>
#include <cstdint>

// GF(2) encoder: out[b][n] = parity( x_row[b] & g_row[n] ).
// B=131072, K=512, N=1024.
//
// R16 = R15 (156us) + 2-tile double-buffered pipeline per block:
//   phase A: pack tile0 (64 rows) -> LDS buf0 (wave wv: 16 exclusive rows)
//   middle:  compute tile0 (stores) with tile1 pack woven in 1-per-4 rows
//   phase C: compute tile1.
// Rationale: R15 blocks are read-only in pack / write-only in compute ->
// chip-wide read/write epochs partially correlate (1280 blocks co-resident);
// copy ceiling (6.29 TB/s, m13) needs both streams flowing continuously.
// Middle phase mixes reads+writes in every wave's instruction stream.
// Live VGPR ~94 (g 64 + q 8 + pf 8 + acc 4 + addr ~10) <= cap 102 @ LB(256,5).
// Component-major bit order identical to pack256 (G): chunk of 256 floats
// -> 4 u64, word j bit i = elem[i*4+j]; row = 2 chunks = 8 u64 = 16 u32.

typedef float f32x4 __attribute__((ext_vector_type(4)));

// ---------------------------------------------------------------------------
// Pack G only: one wave per 256-float chunk. nChunks = N*K/256 = 2048.
__global__ void pack256_kernel(const float* __restrict__ in,
                               unsigned long long* __restrict__ out,
                               int nChunks) {
    const int chunk = blockIdx.x * (blockDim.x >> 6) + (threadIdx.x >> 6);
    const int lane = threadIdx.x & 63;
    if (chunk >= nChunks) return;
    const float4 v =
        reinterpret_cast<const float4*>(in + (size_t)chunk * 256)[lane];
    unsigned long long m0 = __ballot(v.x != 0.0f);
    unsigned long long m1 = __ballot(v.y != 0.0f);
    unsigned long long m2 = __ballot(v.z != 0.0f);
    unsigned long long m3 = __ballot(v.w != 0.0f);
    if (lane == 0) {
        unsigned long long* o = out + (size_t)chunk * 4;
        o[0] = m0; o[1] = m1; o[2] = m2; o[3] = m3;
    }
}

// ---------------------------------------------------------------------------
__global__ __launch_bounds__(256, 5) void gf2_fused_kernel(
    const float* __restrict__ x,      // [B][512] 0/1 floats
    const uint32_t* __restrict__ gp,  // [N][16] packed G rows
    float* __restrict__ out) {        // [B][1024]
    __shared__ uint32_t xl[2][64 * 16];  // two 4 KiB tile buffers

    const int tid = threadIdx.x;
    const int lane = tid & 63;
    const int wv = tid >> 6;
    const long long b0 = (long long)blockIdx.x * 128;

    // This thread's 4 G rows (64 VGPRs). G packed = 64 KiB -> L2-resident.
    uint32_t g[4][16];
#pragma unroll
    for (int j = 0; j < 4; ++j) {
        const uint4* gr =
            reinterpret_cast<const uint4*>(gp + (size_t)(tid * 4 + j) * 16);
        uint4 a = gr[0], b = gr[1], c = gr[2], d = gr[3];
        g[j][0] = a.x;  g[j][1] = a.y;  g[j][2] = a.z;  g[j][3] = a.w;
        g[j][4] = b.x;  g[j][5] = b.y;  g[j][6] = b.z;  g[j][7] = b.w;
        g[j][8] = c.x;  g[j][9] = c.y;  g[j][10] = c.z; g[j][11] = c.w;
        g[j][12] = d.x; g[j][13] = d.y; g[j][14] = d.z; g[j][15] = d.w;
    }

    // Ballot-pack one row held in c0,c1 into LDS buf row `dstrow`.
#define PACKROW(buf, dstrow, c0, c1)                                        \
    do {                                                                    \
        unsigned long long m0 = __ballot(c0.x != 0.0f);                     \
        unsigned long long m1 = __ballot(c0.y != 0.0f);                     \
        unsigned long long m2 = __ballot(c0.z != 0.0f);                     \
        unsigned long long m3 = __ballot(c0.w != 0.0f);                     \
        unsigned long long m4 = __ballot(c1.x != 0.0f);                     \
        unsigned long long m5 = __ballot(c1.y != 0.0f);                     \
        unsigned long long m6 = __ballot(c1.z != 0.0f);                     \
        unsigned long long m7 = __ballot(c1.w != 0.0f);                     \
        if (lane == 0) {                                                    \
            uint4* dst = reinterpret_cast<uint4*>(&xl[buf][(dstrow)*16]);   \
            dst[0] = make_uint4((uint32_t)m0, (uint32_t)(m0 >> 32),         \
                                (uint32_t)m1, (uint32_t)(m1 >> 32));        \
            dst[1] = make_uint4((uint32_t)m2, (uint32_t)(m2 >> 32),         \
                                (uint32_t)m3, (uint32_t)(m3 >> 32));        \
            dst[2] = make_uint4((uint32_t)m4, (uint32_t)(m4 >> 32),         \
                                (uint32_t)m5, (uint32_t)(m5 >> 32));        \
            dst[3] = make_uint4((uint32_t)m6, (uint32_t)(m6 >> 32),         \
                                (uint32_t)m7, (uint32_t)(m7 >> 32));        \
        }                                                                   \
    } while (0)

    // Compute output row `gr_row` from LDS buf row `rr` (q in 2 halves).
#define COMPUTE(buf, rr, gr_row)                                            \
    do {                                                                    \
        const uint4* xr4 = reinterpret_cast<const uint4*>(&xl[buf][(rr)*16]); \
        uint4 q0 = xr4[0], q1 = xr4[1];                                     \
        uint32_t a0, a1, a2, a3;                                            \
        a0 = q0.x & g[0][0];  a1 = q0.x & g[1][0];                          \
        a2 = q0.x & g[2][0];  a3 = q0.x & g[3][0];                          \
        a0 ^= q0.y & g[0][1]; a1 ^= q0.y & g[1][1];                         \
        a2 ^= q0.y & g[2][1]; a3 ^= q0.y & g[3][1];                         \
        a0 ^= q0.z & g[0][2]; a1 ^= q0.z & g[1][2];                         \
        a2 ^= q0.z & g[2][2]; a3 ^= q0.z & g[3][2];                         \
        a0 ^= q0.w & g[0][3]; a1 ^= q0.w & g[1][3];                         \
        a2 ^= q0.w & g[2][3]; a3 ^= q0.w & g[3][3];                         \
        a0 ^= q1.x & g[0][4]; a1 ^= q1.x & g[1][4];                         \
        a2 ^= q1.x & g[2][4]; a3 ^= q1.x & g[3][4];                         \
        a0 ^= q1.y & g[0][5]; a1 ^= q1.y & g[1][5];                         \
        a2 ^= q1.y & g[2][5]; a3 ^= q1.y & g[3][5];                         \
        a0 ^= q1.z & g[0][6]; a1 ^= q1.z & g[1][6];                         \
        a2 ^= q1.z & g[2][6]; a3 ^= q1.z & g[3][6];                         \
        a0 ^= q1.w & g[0][7]; a1 ^= q1.w & g[1][7];                         \
        a2 ^= q1.w & g[2][7]; a3 ^= q1.w & g[3][7];                         \
        q0 = xr4[2]; q1 = xr4[3];                                           \
        a0 ^= q0.x & g[0][8];  a1 ^= q0.x & g[1][8];                        \
        a2 ^= q0.x & g[2][8];  a3 ^= q0.x & g[3][8];                        \
        a0 ^= q0.y & g[0][9];  a1 ^= q0.y & g[1][9];                        \
        a2 ^= q0.y & g[2][9];  a3 ^= q0.y & g[3][9];                        \
        a0 ^= q0.z & g[0][10]; a1 ^= q0.z & g[1][10];                       \
        a2 ^= q0.z & g[2][10]; a3 ^= q0.z & g[3][10];                       \
        a0 ^= q0.w & g[0][11]; a1 ^= q0.w & g[1][11];                       \
        a2 ^= q0.w & g[2][11]; a3 ^= q0.w & g[3][11];                       \
        a0 ^= q1.x & g[0][12]; a1 ^= q1.x & g[1][12];                       \
        a2 ^= q1.x & g[2][12]; a3 ^= q1.x & g[3][12];                       \
        a0 ^= q1.y & g[0][13]; a1 ^= q1.y & g[1][13];                       \
        a2 ^= q1.y & g[2][13]; a3 ^= q1.y & g[3][13];                       \
        a0 ^= q1.z & g[0][14]; a1 ^= q1.z & g[1][14];                       \
        a2 ^= q1.z & g[2][14]; a3 ^= q1.z & g[3][14];                       \
        a0 ^= q1.w & g[0][15]; a1 ^= q1.w & g[1][15];                       \
        a2 ^= q1.w & g[2][15]; a3 ^= q1.w & g[3][15];                       \
        f32x4 o;                                                            \
        o.x = (float)(__popc(a0) & 1);                                      \
        o.y = (float)(__popc(a1) & 1);                                      \
        o.z = (float)(__popc(a2) & 1);                                      \
        o.w = (float)(__popc(a3) & 1);                                      \
        __builtin_nontemporal_store(                                        \
            o, reinterpret_cast<f32x4*>(out + (size_t)(gr_row)*1024) + tid);\
    } while (0)

    // ---- Phase A: pack tile0 (wave's 16 exclusive rows), depth-1 pf. ----
    {
        const float* xr = x + (b0 + wv * 16) * 512 + lane * 4;
        float4 p0 = *reinterpret_cast<const float4*>(xr);
        float4 p1 = *reinterpret_cast<const float4*>(xr + 256);
        for (int r = 0; r < 16; ++r) {
            const float4 c0 = p0, c1 = p1;
            if (r < 15) {
                xr += 512;
                p0 = *reinterpret_cast<const float4*>(xr);
                p1 = *reinterpret_cast<const float4*>(xr + 256);
            }
            PACKROW(0, wv * 16 + r, c0, c1);
        }
    }
    // Prefetch tile1's first pack row before the barrier (latency cover).
    const float* xr1 = x + (b0 + 64 + wv * 16) * 512 + lane * 4;
    float4 pf0 = *reinterpret_cast<const float4*>(xr1);
    float4 pf1 = *reinterpret_cast<const float4*>(xr1 + 256);
    __syncthreads();

    // ---- Middle: compute tile0, tile1 pack woven in at 1-per-4 rows. ----
    {
        int k = 0;
#pragma unroll 4
        for (int r = 0; r < 64; ++r) {
            COMPUTE(0, r, b0 + r);
            if ((r & 3) == 3) {
                const float4 c0 = pf0, c1 = pf1;
                if (k < 15) {
                    xr1 += 512;
                    pf0 = *reinterpret_cast<const float4*>(xr1);
                    pf1 = *reinterpret_cast<const float4*>(xr1 + 256);
                }
                PACKROW(1, wv * 16 + k, c0, c1);
                ++k;
            }
        }
    }
    __syncthreads();

    // ---- Phase C: compute tile1. ----
#pragma unroll 2
    for (int r = 0; r < 64; ++r) {
        COMPUTE(1, r, b0 + 64 + r);
    }
#undef PACKROW
#undef COMPUTE
}

// ---------------------------------------------------------------------------
extern "C" void kernel_launch(void* const* d_in, const int* in_sizes, int n_in,
                              void* d_out, int out_size, void* d_ws, size_t ws_size,
                              hipStream_t stream) {
    const float* x = (const float*)d_in[0];   // [B][512]
    const float* G = (const float*)d_in[1];   // [N][512]
    float* out = (float*)d_out;

    const int B = 131072;
    // Workspace: gp (64 KiB)
    unsigned long long* gp64 = (unsigned long long*)d_ws;

    // Pack G: 2048 chunks, 4 waves/block -> 512 blocks.
    pack256_kernel<<<512, 256, 0, stream>>>(G, gp64, 2048);
    // Fused pipelined pack+encode: one block per 128 rows.
    gf2_fused_kernel<<<B / 128, 256, 0, stream>>>(
        x, (const uint32_t*)gp64, out);
}

// Round 17
// 159.550 us; speedup vs baseline: 1.9864x; 1.9864x over previous
//
#include <hip/hip_runtime.h>
#include <cstdint>

// GF(2) encoder: out[b][n] = parity( x_row[b] & g_row[n] ).
// B=131072, K=512, N=1024.
//
// R17 = R16 (2-tile pipelined pack/compute) with LB(256,5) -> LB(256,4).
// R16's spill: pipeline state pushed live VGPR past the ~102 cap at 5
// blocks/CU -> allocator collapsed to 48 VGPR, g[] in scratch, 360us.
// Cap 128 (4 blocks/CU) holds the same register set spill-free in R13/R14.
//   phase A: pack tile0 (64 rows) -> LDS buf0 (wave wv: 16 exclusive rows)
//   middle:  compute tile0 (nt stores) with tile1 pack woven in 1-per-4
//   phase C: compute tile1.
// Component-major bit order identical to pack256 (G): chunk of 256 floats
// -> 4 u64, word j bit i = elem[i*4+j]; row = 2 chunks = 8 u64 = 16 u32.

typedef float f32x4 __attribute__((ext_vector_type(4)));

// ---------------------------------------------------------------------------
// Pack G only: one wave per 256-float chunk. nChunks = N*K/256 = 2048.
__global__ void pack256_kernel(const float* __restrict__ in,
                               unsigned long long* __restrict__ out,
                               int nChunks) {
    const int chunk = blockIdx.x * (blockDim.x >> 6) + (threadIdx.x >> 6);
    const int lane = threadIdx.x & 63;
    if (chunk >= nChunks) return;
    const float4 v =
        reinterpret_cast<const float4*>(in + (size_t)chunk * 256)[lane];
    unsigned long long m0 = __ballot(v.x != 0.0f);
    unsigned long long m1 = __ballot(v.y != 0.0f);
    unsigned long long m2 = __ballot(v.z != 0.0f);
    unsigned long long m3 = __ballot(v.w != 0.0f);
    if (lane == 0) {
        unsigned long long* o = out + (size_t)chunk * 4;
        o[0] = m0; o[1] = m1; o[2] = m2; o[3] = m3;
    }
}

// ---------------------------------------------------------------------------
__global__ __launch_bounds__(256, 4) void gf2_fused_kernel(
    const float* __restrict__ x,      // [B][512] 0/1 floats
    const uint32_t* __restrict__ gp,  // [N][16] packed G rows
    float* __restrict__ out) {        // [B][1024]
    __shared__ uint32_t xl[2][64 * 16];  // two 4 KiB tile buffers

    const int tid = threadIdx.x;
    const int lane = tid & 63;
    const int wv = tid >> 6;
    const long long b0 = (long long)blockIdx.x * 128;

    // This thread's 4 G rows (64 VGPRs). G packed = 64 KiB -> L2-resident.
    uint32_t g[4][16];
#pragma unroll
    for (int j = 0; j < 4; ++j) {
        const uint4* gr =
            reinterpret_cast<const uint4*>(gp + (size_t)(tid * 4 + j) * 16);
        uint4 a = gr[0], b = gr[1], c = gr[2], d = gr[3];
        g[j][0] = a.x;  g[j][1] = a.y;  g[j][2] = a.z;  g[j][3] = a.w;
        g[j][4] = b.x;  g[j][5] = b.y;  g[j][6] = b.z;  g[j][7] = b.w;
        g[j][8] = c.x;  g[j][9] = c.y;  g[j][10] = c.z; g[j][11] = c.w;
        g[j][12] = d.x; g[j][13] = d.y; g[j][14] = d.z; g[j][15] = d.w;
    }

    // Ballot-pack one row held in c0,c1 into LDS buf row `dstrow`.
#define PACKROW(buf, dstrow, c0, c1)                                        \
    do {                                                                    \
        unsigned long long m0 = __ballot(c0.x != 0.0f);                     \
        unsigned long long m1 = __ballot(c0.y != 0.0f);                     \
        unsigned long long m2 = __ballot(c0.z != 0.0f);                     \
        unsigned long long m3 = __ballot(c0.w != 0.0f);                     \
        unsigned long long m4 = __ballot(c1.x != 0.0f);                     \
        unsigned long long m5 = __ballot(c1.y != 0.0f);                     \
        unsigned long long m6 = __ballot(c1.z != 0.0f);                     \
        unsigned long long m7 = __ballot(c1.w != 0.0f);                     \
        if (lane == 0) {                                                    \
            uint4* dst = reinterpret_cast<uint4*>(&xl[buf][(dstrow)*16]);   \
            dst[0] = make_uint4((uint32_t)m0, (uint32_t)(m0 >> 32),         \
                                (uint32_t)m1, (uint32_t)(m1 >> 32));        \
            dst[1] = make_uint4((uint32_t)m2, (uint32_t)(m2 >> 32),         \
                                (uint32_t)m3, (uint32_t)(m3 >> 32));        \
            dst[2] = make_uint4((uint32_t)m4, (uint32_t)(m4 >> 32),         \
                                (uint32_t)m5, (uint32_t)(m5 >> 32));        \
            dst[3] = make_uint4((uint32_t)m6, (uint32_t)(m6 >> 32),         \
                                (uint32_t)m7, (uint32_t)(m7 >> 32));        \
        }                                                                   \
    } while (0)

    // Compute output row `gr_row` from LDS buf row `rr` (q in 2 halves).
#define COMPUTE(buf, rr, gr_row)                                            \
    do {                                                                    \
        const uint4* xr4 = reinterpret_cast<const uint4*>(&xl[buf][(rr)*16]); \
        uint4 q0 = xr4[0], q1 = xr4[1];                                     \
        uint32_t a0, a1, a2, a3;                                            \
        a0 = q0.x & g[0][0];  a1 = q0.x & g[1][0];                          \
        a2 = q0.x & g[2][0];  a3 = q0.x & g[3][0];                          \
        a0 ^= q0.y & g[0][1]; a1 ^= q0.y & g[1][1];                         \
        a2 ^= q0.y & g[2][1]; a3 ^= q0.y & g[3][1];                         \
        a0 ^= q0.z & g[0][2]; a1 ^= q0.z & g[1][2];                         \
        a2 ^= q0.z & g[2][2]; a3 ^= q0.z & g[3][2];                         \
        a0 ^= q0.w & g[0][3]; a1 ^= q0.w & g[1][3];                         \
        a2 ^= q0.w & g[2][3]; a3 ^= q0.w & g[3][3];                         \
        a0 ^= q1.x & g[0][4]; a1 ^= q1.x & g[1][4];                         \
        a2 ^= q1.x & g[2][4]; a3 ^= q1.x & g[3][4];                         \
        a0 ^= q1.y & g[0][5]; a1 ^= q1.y & g[1][5];                         \
        a2 ^= q1.y & g[2][5]; a3 ^= q1.y & g[3][5];                         \
        a0 ^= q1.z & g[0][6]; a1 ^= q1.z & g[1][6];                         \
        a2 ^= q1.z & g[2][6]; a3 ^= q1.z & g[3][6];                         \
        a0 ^= q1.w & g[0][7]; a1 ^= q1.w & g[1][7];                         \
        a2 ^= q1.w & g[2][7]; a3 ^= q1.w & g[3][7];                         \
        q0 = xr4[2]; q1 = xr4[3];                                           \
        a0 ^= q0.x & g[0][8];  a1 ^= q0.x & g[1][8];                        \
        a2 ^= q0.x & g[2][8];  a3 ^= q0.x & g[3][8];                        \
        a0 ^= q0.y & g[0][9];  a1 ^= q0.y & g[1][9];                        \
        a2 ^= q0.y & g[2][9];  a3 ^= q0.y & g[3][9];                        \
        a0 ^= q0.z & g[0][10]; a1 ^= q0.z & g[1][10];                       \
        a2 ^= q0.z & g[2][10]; a3 ^= q0.z & g[3][10];                       \
        a0 ^= q0.w & g[0][11]; a1 ^= q0.w & g[1][11];                       \
        a2 ^= q0.w & g[2][11]; a3 ^= q0.w & g[3][11];                       \
        a0 ^= q1.x & g[0][12]; a1 ^= q1.x & g[1][12];                       \
        a2 ^= q1.x & g[2][12]; a3 ^= q1.x & g[3][12];                       \
        a0 ^= q1.y & g[0][13]; a1 ^= q1.y & g[1][13];                       \
        a2 ^= q1.y & g[2][13]; a3 ^= q1.y & g[3][13];                       \
        a0 ^= q1.z & g[0][14]; a1 ^= q1.z & g[1][14];                       \
        a2 ^= q1.z & g[2][14]; a3 ^= q1.z & g[3][14];                       \
        a0 ^= q1.w & g[0][15]; a1 ^= q1.w & g[1][15];                       \
        a2 ^= q1.w & g[2][15]; a3 ^= q1.w & g[3][15];                       \
        f32x4 o;                                                            \
        o.x = (float)(__popc(a0) & 1);                                      \
        o.y = (float)(__popc(a1) & 1);                                      \
        o.z = (float)(__popc(a2) & 1);                                      \
        o.w = (float)(__popc(a3) & 1);                                      \
        __builtin_nontemporal_store(                                        \
            o, reinterpret_cast<f32x4*>(out + (size_t)(gr_row)*1024) + tid);\
    } while (0)

    // ---- Phase A: pack tile0 (wave's 16 exclusive rows), depth-1 pf. ----
    {
        const float* xr = x + (b0 + wv * 16) * 512 + lane * 4;
        float4 p0 = *reinterpret_cast<const float4*>(xr);
        float4 p1 = *reinterpret_cast<const float4*>(xr + 256);
        for (int r = 0; r < 16; ++r) {
            const float4 c0 = p0, c1 = p1;
            if (r < 15) {
                xr += 512;
                p0 = *reinterpret_cast<const float4*>(xr);
                p1 = *reinterpret_cast<const float4*>(xr + 256);
            }
            PACKROW(0, wv * 16 + r, c0, c1);
        }
    }
    // Prefetch tile1's first pack row before the barrier (latency cover).
    const float* xr1 = x + (b0 + 64 + wv * 16) * 512 + lane * 4;
    float4 pf0 = *reinterpret_cast<const float4*>(xr1);
    float4 pf1 = *reinterpret_cast<const float4*>(xr1 + 256);
    __syncthreads();

    // ---- Middle: compute tile0, tile1 pack woven in at 1-per-4 rows. ----
    {
        int k = 0;
#pragma unroll 4
        for (int r = 0; r < 64; ++r) {
            COMPUTE(0, r, b0 + r);
            if ((r & 3) == 3) {
                const float4 c0 = pf0, c1 = pf1;
                if (k < 15) {
                    xr1 += 512;
                    pf0 = *reinterpret_cast<const float4*>(xr1);
                    pf1 = *reinterpret_cast<const float4*>(xr1 + 256);
                }
                PACKROW(1, wv * 16 + k, c0, c1);
                ++k;
            }
        }
    }
    __syncthreads();

    // ---- Phase C: compute tile1. ----
#pragma unroll 2
    for (int r = 0; r < 64; ++r) {
        COMPUTE(1, r, b0 + 64 + r);
    }
#undef PACKROW
#undef COMPUTE
}

// ---------------------------------------------------------------------------
extern "C" void kernel_launch(void* const* d_in, const int* in_sizes, int n_in,
                              void* d_out, int out_size, void* d_ws, size_t ws_size,
                              hipStream_t stream) {
    const float* x = (const float*)d_in[0];   // [B][512]
    const float* G = (const float*)d_in[1];   // [N][512]
    float* out = (float*)d_out;

    const int B = 131072;
    // Workspace: gp (64 KiB)
    unsigned long long* gp64 = (unsigned long long*)d_ws;

    // Pack G: 2048 chunks, 4 waves/block -> 512 blocks.
    pack256_kernel<<<512, 256, 0, stream>>>(G, gp64, 2048);
    // Fused pipelined pack+encode: one block per 128 rows.
    gf2_fused_kernel<<<B / 128, 256, 0, stream>>>(
        x, (const uint32_t*)gp64, out);
}

// Round 18
// 157.693 us; speedup vs baseline: 2.0098x; 1.0118x over previous
//
#include <hip/hip_runtime.h>
#include <cstdint>

// GF(2) encoder: out[b][n] = parity( x_row[b] & g_row[n] ).
// B=131072, K=512, N=1024.
//
// FINAL (R18 = R15 verbatim, the champion at 156us; R16/R17's pipelined
// interleave was flat-to-worse, falsifying the stream-correlation theory).
//
// Structure: pack G (64 KiB, one small kernel) + ONE fused kernel:
//   pack phase: wave wv ballot-packs 16 EXCLUSIVE x rows -> LDS (4 KiB);
//               x is read from HBM exactly once (R14: eliminating the 4x
//               redundant re-reads was -28us; they were missing L2).
//   compute:    per row, broadcast ds_read_b128 delivers packed row;
//               AND/XOR vs G in VGPRs (4 cols/thread); NONTEMPORAL f32x4
//               stores (R13: write stream bypasses L2, -16us).
// LB(256,5): cap ~102 >= ~92 live, 5 blocks/CU (R15: +3us over 4).
// Ledger: 148us fused / 768 MB = 5.2 TB/s = 82% of 6.29 TB/s copy ceiling.
// Component-major bit order identical for x and G (parity-invariant):
// chunk of 256 floats -> 4 u64, word j bit i = elem[i*4+j].

typedef float f32x4 __attribute__((ext_vector_type(4)));

// ---------------------------------------------------------------------------
// Pack G only: one wave per 256-float chunk. nChunks = N*K/256 = 2048.
__global__ void pack256_kernel(const float* __restrict__ in,
                               unsigned long long* __restrict__ out,
                               int nChunks) {
    const int chunk = blockIdx.x * (blockDim.x >> 6) + (threadIdx.x >> 6);
    const int lane = threadIdx.x & 63;
    if (chunk >= nChunks) return;
    const float4 v =
        reinterpret_cast<const float4*>(in + (size_t)chunk * 256)[lane];
    unsigned long long m0 = __ballot(v.x != 0.0f);
    unsigned long long m1 = __ballot(v.y != 0.0f);
    unsigned long long m2 = __ballot(v.z != 0.0f);
    unsigned long long m3 = __ballot(v.w != 0.0f);
    if (lane == 0) {
        unsigned long long* o = out + (size_t)chunk * 4;
        o[0] = m0; o[1] = m1; o[2] = m2; o[3] = m3;
    }
}

// ---------------------------------------------------------------------------
// Fused encode: 256 threads, 4 cols/thread (block covers N=1024).
__global__ __launch_bounds__(256, 5) void gf2_fused_kernel(
    const float* __restrict__ x,      // [B][512] 0/1 floats
    const uint32_t* __restrict__ gp,  // [N][16] packed G rows
    float* __restrict__ out) {        // [B][1024]
    __shared__ uint32_t xl[64 * 16];  // 64 rows x 16 u32 = 4 KiB

    const int tid = threadIdx.x;
    const int lane = tid & 63;
    const int wv = tid >> 6;
    const long long b0 = (long long)blockIdx.x * 64;

    // This thread's 4 G rows (64 VGPRs). G packed = 64 KiB -> L2-resident.
    uint32_t g[4][16];
#pragma unroll
    for (int j = 0; j < 4; ++j) {
        const uint4* gr =
            reinterpret_cast<const uint4*>(gp + (size_t)(tid * 4 + j) * 16);
        uint4 a = gr[0], b = gr[1], c = gr[2], d = gr[3];
        g[j][0] = a.x;  g[j][1] = a.y;  g[j][2] = a.z;  g[j][3] = a.w;
        g[j][4] = b.x;  g[j][5] = b.y;  g[j][6] = b.z;  g[j][7] = b.w;
        g[j][8] = c.x;  g[j][9] = c.y;  g[j][10] = c.z; g[j][11] = c.w;
        g[j][12] = d.x; g[j][13] = d.y; g[j][14] = d.z; g[j][15] = d.w;
    }

    // ---- Pack phase: 16 exclusive rows per wave, depth-1 prefetch. ----
    {
        const float* xr = x + (b0 + wv * 16) * 512 + lane * 4;
        float4 p0 = *reinterpret_cast<const float4*>(xr);
        float4 p1 = *reinterpret_cast<const float4*>(xr + 256);
        for (int r = 0; r < 16; ++r) {
            const float4 c0 = p0, c1 = p1;
            if (r < 15) {
                xr += 512;
                p0 = *reinterpret_cast<const float4*>(xr);
                p1 = *reinterpret_cast<const float4*>(xr + 256);
            }
            unsigned long long m0 = __ballot(c0.x != 0.0f);
            unsigned long long m1 = __ballot(c0.y != 0.0f);
            unsigned long long m2 = __ballot(c0.z != 0.0f);
            unsigned long long m3 = __ballot(c0.w != 0.0f);
            unsigned long long m4 = __ballot(c1.x != 0.0f);
            unsigned long long m5 = __ballot(c1.y != 0.0f);
            unsigned long long m6 = __ballot(c1.z != 0.0f);
            unsigned long long m7 = __ballot(c1.w != 0.0f);
            if (lane == 0) {
                uint4* dst = reinterpret_cast<uint4*>(&xl[(wv * 16 + r) * 16]);
                dst[0] = make_uint4((uint32_t)m0, (uint32_t)(m0 >> 32),
                                    (uint32_t)m1, (uint32_t)(m1 >> 32));
                dst[1] = make_uint4((uint32_t)m2, (uint32_t)(m2 >> 32),
                                    (uint32_t)m3, (uint32_t)(m3 >> 32));
                dst[2] = make_uint4((uint32_t)m4, (uint32_t)(m4 >> 32),
                                    (uint32_t)m5, (uint32_t)(m5 >> 32));
                dst[3] = make_uint4((uint32_t)m6, (uint32_t)(m6 >> 32),
                                    (uint32_t)m7, (uint32_t)(m7 >> 32));
            }
        }
    }
    __syncthreads();

    // ---- Compute phase: 64 rows from LDS (broadcast), nt stores. ----
    for (int r = 0; r < 64; ++r) {
        const uint4* xr4 = reinterpret_cast<const uint4*>(&xl[r * 16]);
        uint4 q0 = xr4[0], q1 = xr4[1], q2 = xr4[2], q3 = xr4[3];
        const uint32_t xv[16] = {q0.x, q0.y, q0.z, q0.w,
                                 q1.x, q1.y, q1.z, q1.w,
                                 q2.x, q2.y, q2.z, q2.w,
                                 q3.x, q3.y, q3.z, q3.w};
        uint32_t a0 = 0, a1 = 0, a2 = 0, a3 = 0;
#pragma unroll
        for (int i = 0; i < 16; ++i) {
            a0 ^= xv[i] & g[0][i];
            a1 ^= xv[i] & g[1][i];
            a2 ^= xv[i] & g[2][i];
            a3 ^= xv[i] & g[3][i];
        }
        f32x4 o;
        o.x = (float)(__popc(a0) & 1);
        o.y = (float)(__popc(a1) & 1);
        o.z = (float)(__popc(a2) & 1);
        o.w = (float)(__popc(a3) & 1);
        __builtin_nontemporal_store(
            o, reinterpret_cast<f32x4*>(out + (size_t)(b0 + r) * 1024) + tid);
    }
}

// ---------------------------------------------------------------------------
extern "C" void kernel_launch(void* const* d_in, const int* in_sizes, int n_in,
                              void* d_out, int out_size, void* d_ws, size_t ws_size,
                              hipStream_t stream) {
    const float* x = (const float*)d_in[0];   // [B][512]
    const float* G = (const float*)d_in[1];   // [N][512]
    float* out = (float*)d_out;

    const int B = 131072;
    // Workspace: gp (64 KiB)
    unsigned long long* gp64 = (unsigned long long*)d_ws;

    // Pack G: 2048 chunks, 4 waves/block -> 512 blocks.
    pack256_kernel<<<512, 256, 0, stream>>>(G, gp64, 2048);
    // Fused ballot-pack + encode: one block per 64 rows.
    gf2_fused_kernel<<<B / 64, 256, 0, stream>>>(
        x, (const uint32_t*)gp64, out);
}